// Round 2
// baseline (565.222 us; speedup 1.0000x reference)
//
#include <hip/hip_runtime.h>

// ---- problem constants ----
#define V_DIM   2048
#define Q_DIM   1024
#define NUM_HID 1024
#define BB 64
#define KK 12
#define NN 36
#define M_ROWS (BB*KK*NN)    // 27648 = 108 * 256, exact
#define BKROWS (BB*KK)       // 768

typedef unsigned short u16;
typedef __bf16 bf16x8  __attribute__((ext_vector_type(8)));
typedef u16    ushort8 __attribute__((ext_vector_type(8)));
typedef float  floatx4 __attribute__((ext_vector_type(4)));

__device__ __forceinline__ u16 f2bf(float f) {
    unsigned u = __float_as_uint(f);
    u += 0x7fffu + ((u >> 16) & 1u);
    return (u16)(u >> 16);
}

__device__ __forceinline__ void gload16(const u16* g, u16* l) {
    __builtin_amdgcn_global_load_lds((const __attribute__((address_space(1))) void*)g,
                                     (__attribute__((address_space(3))) void*)l, 16, 0, 0);
}

// raw barrier with compiler-level memory fence (NO vmcnt drain, unlike __syncthreads)
__device__ __forceinline__ void barrier_() {
    asm volatile("" ::: "memory");
    __builtin_amdgcn_s_barrier();
    asm volatile("" ::: "memory");
}
__device__ __forceinline__ void lgkm0_() {
    asm volatile("s_waitcnt lgkmcnt(0)" ::: "memory");
    __builtin_amdgcn_sched_barrier(0);
}

// ---- ||W1||^2 ----
__global__ void norm_w1_kernel(const float* __restrict__ W1, float* __restrict__ acc)
{
    float s = 0.f;
    const float4* p = (const float4*)W1;
    const int total = (NUM_HID * (V_DIM + Q_DIM)) / 4;
    for (int i = blockIdx.x * 256 + threadIdx.x; i < total; i += 256 * 256) {
        float4 f = p[i];
        s += f.x * f.x + f.y * f.y + f.z * f.z + f.w * f.w;
    }
    #pragma unroll
    for (int off = 32; off > 0; off >>= 1) s += __shfl_down(s, off);
    __shared__ float red[4];
    if ((threadIdx.x & 63) == 0) red[threadIdx.x >> 6] = s;
    __syncthreads();
    if (threadIdx.x == 0) atomicAdd(acc, red[0] + red[1] + red[2] + red[3]);
}

// ---- ||W2||^2 + scales ----
__global__ void scale_kernel(const float* __restrict__ W2, const float* __restrict__ g1,
                             const float* __restrict__ g2, float* __restrict__ wsf)
{
    float v = W2[threadIdx.x];
    float s = v * v;
    #pragma unroll
    for (int off = 32; off > 0; off >>= 1) s += __shfl_down(s, off);
    __shared__ float red[16];
    if ((threadIdx.x & 63) == 0) red[threadIdx.x >> 6] = s;
    __syncthreads();
    if (threadIdx.x == 0) {
        float t = 0.f;
        #pragma unroll
        for (int u = 0; u < 16; u++) t += red[u];
        wsf[2] = g1[0] / sqrtf(wsf[0]);
        wsf[3] = g2[0] / sqrtf(t);
    }
}

// ---- W1 -> bf16 split ----
__global__ void convert_w1_kernel(const float* __restrict__ W1,
                                  u16* __restrict__ W1v, u16* __restrict__ W1q)
{
    int s = blockIdx.x * 256 + threadIdx.x;
    if (s >= NUM_HID * (V_DIM + Q_DIM) / 8) return;
    int h = s / 384, g = s % 384;
    const float4* p = (const float4*)(W1 + (size_t)h * (V_DIM + Q_DIM) + g * 8);
    float4 a = p[0], b = p[1];
    ushort8 o;
    o[0]=f2bf(a.x); o[1]=f2bf(a.y); o[2]=f2bf(a.z); o[3]=f2bf(a.w);
    o[4]=f2bf(b.x); o[5]=f2bf(b.y); o[6]=f2bf(b.z); o[7]=f2bf(b.w);
    if (g < 256) *(ushort8*)(W1v + (size_t)h * V_DIM + g * 8) = o;
    else         *(ushort8*)(W1q + (size_t)h * Q_DIM + (g - 256) * 8) = o;
}

// ---- v fp32 -> bf16 streaming pass ----
__global__ void convert_v_kernel(const float* __restrict__ v, u16* __restrict__ vbf)
{
    const int total = (M_ROWS * V_DIM) / 8;
    for (int s = blockIdx.x * 256 + threadIdx.x; s < total; s += 2048 * 256) {
        const float4* p = (const float4*)(v + (size_t)s * 8);
        float4 a = p[0], b = p[1];
        ushort8 o;
        o[0]=f2bf(a.x); o[1]=f2bf(a.y); o[2]=f2bf(a.z); o[3]=f2bf(a.w);
        o[4]=f2bf(b.x); o[5]=f2bf(b.y); o[6]=f2bf(b.z); o[7]=f2bf(b.w);
        *(ushort8*)(vbf + (size_t)s * 8) = o;
    }
}

// ======================= 2-phase 128^2 GEMM (hq pass + fallback) =======================
template<int GK, bool MAIN, bool ABF16>
__global__ __launch_bounds__(256, 2)
void gemm_kernel(const void* __restrict__ Asrc,
                 const u16*  __restrict__ Bsrc,
                 float*      __restrict__ outp,
                 const float* __restrict__ hq,
                 const float* __restrict__ b1,
                 const float* __restrict__ W2,
                 const float* __restrict__ scl)
{
    __shared__ u16 As[ABF16 ? 128 * 64 : 128 * 72];
    __shared__ u16 Bs[128 * 64];

    const int tid  = threadIdx.x;
    const int lane = tid & 63;
    const int wv   = tid >> 6;
    const int wm   = wv & 1;
    const int wn   = wv >> 1;
    const int quad = lane >> 4;
    const int l15  = lane & 15;

    const int bid  = blockIdx.y * 8 + blockIdx.x;
    const int nwg  = gridDim.x * gridDim.y;
    const int tile = (bid & 7) * (nwg >> 3) + (bid >> 3);
    const int tx   = tile & 7;
    const int ty   = tile >> 3;
    const int m0   = ty * 128;
    const int n0   = tx * 128;

    floatx4 acc[4][4];
    #pragma unroll
    for (int i = 0; i < 4; i++)
        #pragma unroll
        for (int j = 0; j < 4; j++)
            acc[i][j] = (floatx4){0.f, 0.f, 0.f, 0.f};

    for (int kt = 0; kt < GK / 64; ++kt) {
        const int k0 = kt * 64;
        __syncthreads();
        if constexpr (ABF16) {
            const u16* Ab = (const u16*)Asrc;
            #pragma unroll
            for (int it = 0; it < 4; ++it) {
                int sbase = it * 256 + wv * 64;
                int s = sbase + lane;
                int r = s >> 3, g = s & 7;
                int gs = g ^ (r & 7);
                gload16(Ab + (size_t)(m0 + r) * GK + k0 + gs * 8, &As[sbase * 8]);
            }
        } else {
            const float* Af = (const float*)Asrc;
            #pragma unroll
            for (int it = 0; it < 4; ++it) {
                int s = tid + 256 * it;
                int r = s >> 3, g = s & 7;
                const float4* gp = (const float4*)(Af + (size_t)(m0 + r) * GK + k0 + g * 8);
                float4 f0 = gp[0];
                float4 f1 = gp[1];
                ushort8 o;
                o[0]=f2bf(f0.x); o[1]=f2bf(f0.y); o[2]=f2bf(f0.z); o[3]=f2bf(f0.w);
                o[4]=f2bf(f1.x); o[5]=f2bf(f1.y); o[6]=f2bf(f1.z); o[7]=f2bf(f1.w);
                *(ushort8*)(&As[r * 72 + g * 8]) = o;
            }
        }
        #pragma unroll
        for (int it = 0; it < 4; ++it) {
            int sbase = it * 256 + wv * 64;
            int s = sbase + lane;
            int c = s >> 3, g = s & 7;
            int gs = g ^ (c & 7);
            gload16(Bsrc + (size_t)(n0 + c) * GK + k0 + gs * 8, &Bs[sbase * 8]);
        }
        __syncthreads();
        #pragma unroll
        for (int ks = 0; ks < 2; ++ks) {
            bf16x8 af[4], bfr[4];
            #pragma unroll
            for (int i = 0; i < 4; i++) {
                int rA = wm * 64 + i * 16 + l15;
                if constexpr (ABF16) {
                    int off = (ks * 32 + quad * 8) ^ ((rA & 7) << 3);
                    af[i] = *(const bf16x8*)(&As[rA * 64 + off]);
                } else {
                    af[i] = *(const bf16x8*)(&As[rA * 72 + ks * 32 + quad * 8]);
                }
            }
            #pragma unroll
            for (int j = 0; j < 4; j++) {
                int c = wn * 64 + j * 16 + l15;
                int off = (ks * 32 + quad * 8) ^ ((c & 7) << 3);
                bfr[j] = *(const bf16x8*)(&Bs[c * 64 + off]);
            }
            #pragma unroll
            for (int i = 0; i < 4; i++)
                #pragma unroll
                for (int j = 0; j < 4; j++)
                    acc[i][j] = __builtin_amdgcn_mfma_f32_16x16x32_bf16(af[i], bfr[j], acc[i][j], 0, 0, 0);
        }
    }

    if constexpr (MAIN) {
        const float s1 = scl[2];
        int   cg[4];
        float w2v[4], b1v[4];
        #pragma unroll
        for (int j = 0; j < 4; j++) {
            cg[j]  = n0 + wn * 64 + j * 16 + l15;
            w2v[j] = W2[cg[j]];
            b1v[j] = b1[cg[j]];
        }
        #pragma unroll
        for (int i = 0; i < 4; i++) {
            #pragma unroll
            for (int r = 0; r < 4; r++) {
                const int mg = m0 + wm * 64 + i * 16 + quad * 4 + r;
                const int bk = mg / NN;
                float p = 0.f;
                #pragma unroll
                for (int j = 0; j < 4; j++) {
                    float pre = s1 * (acc[i][j][r] + hq[(size_t)bk * NUM_HID + cg[j]]) + b1v[j];
                    p += fmaxf(pre, 0.f) * w2v[j];
                }
                p += __shfl_xor(p, 1);
                p += __shfl_xor(p, 2);
                p += __shfl_xor(p, 4);
                p += __shfl_xor(p, 8);
                if (l15 == 0)
                    outp[(size_t)mg * 16 + tx * 2 + wn] = p;
            }
        }
    } else {
        #pragma unroll
        for (int i = 0; i < 4; i++)
            #pragma unroll
            for (int r = 0; r < 4; r++) {
                const int mg = m0 + wm * 64 + i * 16 + quad * 4 + r;
                #pragma unroll
                for (int j = 0; j < 4; j++) {
                    const int c = n0 + wn * 64 + j * 16 + l15;
                    outp[(size_t)mg * NUM_HID + c] = acc[i][j][r];
                }
            }
    }
}

// ======================= 8-phase 256^2 main GEMM (T3+T4+T5) =======================
// GK = 2048 (32 K-tiles of BK=64). 512 threads = 8 waves (2M x 4N), per-wave 128x64 out.
// LDS: 2 buffers x (A 256x64 + B 256x64) bf16 = 128 KB. 1 block/CU.
// Per K-tile: 4 phases, each = {ds_reads; stage 1 half-tile (2x gload_lds); barrier;
// lgkmcnt(0); setprio(1); 16 MFMA; setprio(0); barrier}. Counted vmcnt(4) ONCE per
// K-tile at P4. Stage schedule (derived, safe): P1: Ah1(t+1) [other buf, A dead since
// t-1.P3]; P2: Bh1(t+1); P3: Bh0(t+2) [cur buf, B dead after P2]; P4: Ah0(t+2) [A dead
// after P3]. vmcnt(4) at P4 leaves only {P3,P4} stages outstanding -> all of tile t+1
// landed before its first read. Tail: clamped-source dummy stages keep vmcnt counts valid.
__global__ __launch_bounds__(512, 2)
void gemm8_kernel(const u16* __restrict__ Asrc, const u16* __restrict__ Bsrc,
                  float* __restrict__ outp, const float* __restrict__ hq,
                  const float* __restrict__ b1, const float* __restrict__ W2,
                  const float* __restrict__ scl)
{
    __shared__ u16 As[2][256 * 64];
    __shared__ u16 Bs[2][256 * 64];

    const int tid  = threadIdx.x;
    const int lane = tid & 63;
    const int wv   = tid >> 6;        // 0..7
    const int wm   = wv >> 2;         // 0..1
    const int wn   = wv & 3;          // 0..3
    const int quad = lane >> 4;
    const int l15  = lane & 15;
    const int swz  = l15 & 7;

    // XCD swizzle: nwg = 432, 432/8 = 54, n-minor so same-XCD tiles share the A panel
    const int bid  = blockIdx.x;
    const int tile = (bid & 7) * (gridDim.x >> 3) + (bid >> 3);
    const int tx   = tile & 3;
    const int ty   = tile >> 2;
    const int m0   = ty * 256;
    const int n0   = tx * 256;

    // staging constants: slot = tid; row-in-issue = tid>>3; source group pre-swizzled
    const int rg   = tid >> 3;                  // 0..63
    const int gsw  = (tid & 7) ^ (rg & 7);

    // stage one 128-row half-tile (2 issues of 8KB) of tile t into buffer p
    auto stage = [&](int p, int isB, int half, int t) {
        const u16* src = isB ? Bsrc : Asrc;
        const int  b0  = isB ? n0 : m0;
        u16* dst = isB ? Bs[p] : As[p];
        #pragma unroll
        for (int ii = 0; ii < 2; ++ii) {
            const int row = half * 128 + ii * 64 + rg;          // per-lane source row
            u16* d = dst + (size_t)(half * 128 + ii * 64 + wv * 8) * 64;  // wave-uniform
            gload16(src + (size_t)(b0 + row) * 2048 + t * 64 + gsw * 8, d);
        }
    };
    auto rdA = [&](int p, int i, int ks) {
        const int row = wm * 128 + i * 16 + l15;
        return *(const bf16x8*)(&As[p][row * 64 + (((ks * 4 + quad) ^ swz) * 8)]);
    };
    auto rdB = [&](int p, int j, int ks) {
        const int col = wn * 64 + j * 16 + l15;
        return *(const bf16x8*)(&Bs[p][col * 64 + (((ks * 4 + quad) ^ swz) * 8)]);
    };

    floatx4 acc[8][4];
    #pragma unroll
    for (int i = 0; i < 8; i++)
        #pragma unroll
        for (int j = 0; j < 4; j++)
            acc[i][j] = (floatx4){0.f, 0.f, 0.f, 0.f};

    bf16x8 aLo[4][2], aHi[4][2], b01[2][2], b23[2][2];

    // ---- prologue: matches steady-state issue order exactly ----
    stage(0, 1, 0, 0);   // Bh0(0)
    stage(0, 0, 0, 0);   // Ah0(0)
    stage(0, 0, 1, 0);   // Ah1(0)
    stage(0, 1, 1, 0);   // Bh1(0)
    stage(1, 1, 0, 1);   // Bh0(1)
    stage(1, 0, 0, 1);   // Ah0(1)
    asm volatile("s_waitcnt vmcnt(4)" ::: "memory");   // tile 0 fully landed
    barrier_();

    for (int t = 0; t < 32; ++t) {
        const int p  = t & 1;
        const int pn = p ^ 1;
        const int t1 = (t + 1 < 32) ? t + 1 : 30;   // clamped dummy source at tail
        const int t2 = (t + 2 < 32) ? t + 2 : 30;

        // ---- P1: quadrant (i0-3, j0-1); reads 12; stage Ah1(t+1) ----
        #pragma unroll
        for (int i = 0; i < 4; i++) { aLo[i][0] = rdA(p, i, 0); aLo[i][1] = rdA(p, i, 1); }
        #pragma unroll
        for (int j = 0; j < 2; j++) { b01[j][0] = rdB(p, j, 0); b01[j][1] = rdB(p, j, 1); }
        stage(pn, 0, 1, t1);
        barrier_();
        lgkm0_();
        __builtin_amdgcn_s_setprio(1);
        #pragma unroll
        for (int i = 0; i < 4; i++)
            #pragma unroll
            for (int j = 0; j < 2; j++) {
                acc[i][j] = __builtin_amdgcn_mfma_f32_16x16x32_bf16(aLo[i][0], b01[j][0], acc[i][j], 0, 0, 0);
                acc[i][j] = __builtin_amdgcn_mfma_f32_16x16x32_bf16(aLo[i][1], b01[j][1], acc[i][j], 0, 0, 0);
            }
        __builtin_amdgcn_s_setprio(0);
        barrier_();

        // ---- P2: quadrant (i0-3, j2-3); reads 4; stage Bh1(t+1) ----
        #pragma unroll
        for (int j = 0; j < 2; j++) { b23[j][0] = rdB(p, 2 + j, 0); b23[j][1] = rdB(p, 2 + j, 1); }
        stage(pn, 1, 1, t1);
        barrier_();
        lgkm0_();
        __builtin_amdgcn_s_setprio(1);
        #pragma unroll
        for (int i = 0; i < 4; i++)
            #pragma unroll
            for (int j = 0; j < 2; j++) {
                acc[i][2 + j] = __builtin_amdgcn_mfma_f32_16x16x32_bf16(aLo[i][0], b23[j][0], acc[i][2 + j], 0, 0, 0);
                acc[i][2 + j] = __builtin_amdgcn_mfma_f32_16x16x32_bf16(aLo[i][1], b23[j][1], acc[i][2 + j], 0, 0, 0);
            }
        __builtin_amdgcn_s_setprio(0);
        barrier_();

        // ---- P3: quadrant (i4-7, j0-1); reads 8; stage Bh0(t+2) ----
        #pragma unroll
        for (int i = 0; i < 4; i++) { aHi[i][0] = rdA(p, 4 + i, 0); aHi[i][1] = rdA(p, 4 + i, 1); }
        stage(p, 1, 0, t2);
        barrier_();
        lgkm0_();
        __builtin_amdgcn_s_setprio(1);
        #pragma unroll
        for (int i = 0; i < 4; i++)
            #pragma unroll
            for (int j = 0; j < 2; j++) {
                acc[4 + i][j] = __builtin_amdgcn_mfma_f32_16x16x32_bf16(aHi[i][0], b01[j][0], acc[4 + i][j], 0, 0, 0);
                acc[4 + i][j] = __builtin_amdgcn_mfma_f32_16x16x32_bf16(aHi[i][1], b01[j][1], acc[4 + i][j], 0, 0, 0);
            }
        __builtin_amdgcn_s_setprio(0);
        barrier_();

        // ---- P4: quadrant (i4-7, j2-3); no reads; stage Ah0(t+2); vmcnt(4) ----
        stage(p, 0, 0, t2);
        asm volatile("s_waitcnt vmcnt(4)" ::: "memory");
        barrier_();
        __builtin_amdgcn_s_setprio(1);
        #pragma unroll
        for (int i = 0; i < 4; i++)
            #pragma unroll
            for (int j = 0; j < 2; j++) {
                acc[4 + i][2 + j] = __builtin_amdgcn_mfma_f32_16x16x32_bf16(aHi[i][0], b23[j][0], acc[4 + i][2 + j], 0, 0, 0);
                acc[4 + i][2 + j] = __builtin_amdgcn_mfma_f32_16x16x32_bf16(aHi[i][1], b23[j][1], acc[4 + i][2 + j], 0, 0, 0);
            }
        __builtin_amdgcn_s_setprio(0);
        barrier_();
    }

    // ---- fused epilogue ----
    const float s1 = scl[2];
    int   cg[4];
    float w2v[4], b1v[4];
    #pragma unroll
    for (int j = 0; j < 4; j++) {
        cg[j]  = n0 + wn * 64 + j * 16 + l15;
        w2v[j] = W2[cg[j]];
        b1v[j] = b1[cg[j]];
    }
    #pragma unroll
    for (int i = 0; i < 8; i++) {
        #pragma unroll
        for (int r = 0; r < 4; r++) {
            const int mg = m0 + wm * 128 + i * 16 + quad * 4 + r;
            const int bk = mg / NN;
            float pv = 0.f;
            #pragma unroll
            for (int j = 0; j < 4; j++) {
                float pre = s1 * (acc[i][j][r] + hq[(size_t)bk * NUM_HID + cg[j]]) + b1v[j];
                pv += fmaxf(pre, 0.f) * w2v[j];
            }
            pv += __shfl_xor(pv, 1);
            pv += __shfl_xor(pv, 2);
            pv += __shfl_xor(pv, 4);
            pv += __shfl_xor(pv, 8);
            if (l15 == 0)
                outp[(size_t)mg * 16 + tx * 4 + wn] = pv;
        }
    }
}

// ---- softmax over K=12 per (b,n) ----
__global__ void softmax_kernel(const float* __restrict__ part,
                               const float* __restrict__ scl,
                               const float* __restrict__ b2,
                               float* __restrict__ out)
{
    int t = blockIdx.x * 256 + threadIdx.x;
    if (t >= BB * NN) return;
    int b = t / NN, n = t % NN;
    float s2 = scl[3], bias = b2[0];
    float lg[KK];
    float mx = -1e30f;
    #pragma unroll
    for (int k = 0; k < KK; k++) {
        int m = (b * KK + k) * NN + n;
        const float4* pp = (const float4*)(part + (size_t)m * 16);
        float4 a0 = pp[0], a1 = pp[1], a2 = pp[2], a3 = pp[3];
        float s = (a0.x + a0.y + a0.z + a0.w) + (a1.x + a1.y + a1.z + a1.w)
                + (a2.x + a2.y + a2.z + a2.w) + (a3.x + a3.y + a3.z + a3.w);
        lg[k] = s2 * s + bias;
        mx = fmaxf(mx, lg[k]);
    }
    float den = 0.f;
    #pragma unroll
    for (int k = 0; k < KK; k++) { lg[k] = expf(lg[k] - mx); den += lg[k]; }
    float inv = 1.0f / den;
    #pragma unroll
    for (int k = 0; k < KK; k++) out[(size_t)((b * KK + k) * NN + n)] = lg[k] * inv;
}

extern "C" void kernel_launch(void* const* d_in, const int* in_sizes, int n_in,
                              void* d_out, int out_size, void* d_ws, size_t ws_size,
                              hipStream_t stream)
{
    (void)in_sizes; (void)n_in; (void)out_size;
    const float* v  = (const float*)d_in[0];
    const float* q  = (const float*)d_in[1];
    const float* W1 = (const float*)d_in[2];
    const float* g1 = (const float*)d_in[3];
    const float* b1 = (const float*)d_in[4];
    const float* W2 = (const float*)d_in[5];
    const float* g2 = (const float*)d_in[6];
    const float* b2 = (const float*)d_in[7];
    float* out = (float*)d_out;

    char*  ws   = (char*)d_ws;
    float* wsf  = (float*)ws;
    float* hq   = (float*)(ws + 16);
    u16*   W1v  = (u16*)  (ws + 16 + 3145728);
    u16*   W1q  = (u16*)  (ws + 16 + 3145728 + 4194304);
    float* part = (float*)(ws + 16 + 3145728 + 4194304 + 2097152);
    u16*   vbf  = (u16*)  (ws + 16 + 3145728 + 4194304 + 2097152 + 1769472);
    const size_t ws_need = 16ull + 3145728 + 4194304 + 2097152 + 1769472
                         + (size_t)M_ROWS * V_DIM * 2;
    const bool pre = (ws_size >= ws_need);

    hipMemsetAsync(d_ws, 0, 16, stream);
    norm_w1_kernel<<<256, 256, 0, stream>>>(W1, wsf);
    scale_kernel<<<1, 1024, 0, stream>>>(W2, g1, g2, wsf);
    convert_w1_kernel<<<1536, 256, 0, stream>>>(W1, W1v, W1q);
    gemm_kernel<Q_DIM, false, false><<<dim3(8, 6), 256, 0, stream>>>(
        q, W1q, hq, nullptr, nullptr, nullptr, wsf);
    if (pre) {
        convert_v_kernel<<<2048, 256, 0, stream>>>(v, vbf);
        gemm8_kernel<<<432, 512, 0, stream>>>(vbf, W1v, part, hq, b1, W2, wsf);
    } else {
        gemm_kernel<V_DIM, true, false><<<dim3(8, 216), 256, 0, stream>>>(
            v, W1v, part, hq, b1, W2, wsf);
    }
    softmax_kernel<<<9, 256, 0, stream>>>(part, wsf, b2, out);
}

// Round 3
// 537.744 us; speedup vs baseline: 1.0511x; 1.0511x over previous
//
#include <hip/hip_runtime.h>

// ---- problem constants ----
#define V_DIM   2048
#define Q_DIM   1024
#define NUM_HID 1024
#define BB 64
#define KK 12
#define NN 36
#define M_ROWS (BB*KK*NN)    // 27648 = 216 * 128, exact
#define BKROWS (BB*KK)       // 768   = 6 * 128,   exact

typedef unsigned short u16;
typedef __bf16 bf16x8  __attribute__((ext_vector_type(8)));
typedef u16    ushort8 __attribute__((ext_vector_type(8)));
typedef float  floatx4 __attribute__((ext_vector_type(4)));

// fp32 -> bf16 RNE, 2-at-a-time (guide T12: no builtin on gfx950, inline asm verified)
__device__ __forceinline__ unsigned cvtpk(float lo, float hi) {
    unsigned r;
    asm("v_cvt_pk_bf16_f32 %0, %1, %2" : "=v"(r) : "v"(lo), "v"(hi));
    return r;
}

// async global->LDS, 16B per lane. LDS dest = wave-uniform base + lane*16 (HW).
__device__ __forceinline__ void gload16(const u16* g, u16* l) {
    __builtin_amdgcn_global_load_lds((const __attribute__((address_space(1))) void*)g,
                                     (__attribute__((address_space(3))) void*)l, 16, 0, 0);
}

// ---- W1 fp32 (1024 x 3072) -> bf16 W1v (1024x2048) + W1q (1024x1024),
//      FUSED with ||W1||^2 reduction -> atomicAdd into acc[0] ----
__global__ void convert_w1_kernel(const float* __restrict__ W1,
                                  u16* __restrict__ W1v, u16* __restrict__ W1q,
                                  float* __restrict__ acc)
{
    int s = blockIdx.x * 256 + threadIdx.x;          // grid 1536*256 = 393216 exact
    int h = s / 384, g = s % 384;
    const float4* p = (const float4*)(W1 + (size_t)h * (V_DIM + Q_DIM) + g * 8);
    float4 a = p[0], b = p[1];
    float ss = a.x*a.x + a.y*a.y + a.z*a.z + a.w*a.w
             + b.x*b.x + b.y*b.y + b.z*b.z + b.w*b.w;
    unsigned d0 = cvtpk(a.x, a.y), d1 = cvtpk(a.z, a.w);
    unsigned d2 = cvtpk(b.x, b.y), d3 = cvtpk(b.z, b.w);
    uint4 o = make_uint4(d0, d1, d2, d3);
    if (g < 256) *(uint4*)(W1v + (size_t)h * V_DIM + g * 8) = o;
    else         *(uint4*)(W1q + (size_t)h * Q_DIM + (g - 256) * 8) = o;
    #pragma unroll
    for (int off = 32; off > 0; off >>= 1) ss += __shfl_down(ss, off);
    __shared__ float red[4];
    if ((threadIdx.x & 63) == 0) red[threadIdx.x >> 6] = ss;
    __syncthreads();
    if (threadIdx.x == 0) atomicAdd(acc, red[0] + red[1] + red[2] + red[3]);
}

// ---- ||W2||^2 (1024) + final scales: wsf[2]=g1/||W1||, wsf[3]=g2/||W2|| ----
__global__ void scale_kernel(const float* __restrict__ W2, const float* __restrict__ g1,
                             const float* __restrict__ g2, float* __restrict__ wsf)
{
    float v = W2[threadIdx.x];          // blockDim = 1024
    float s = v * v;
    #pragma unroll
    for (int off = 32; off > 0; off >>= 1) s += __shfl_down(s, off);
    __shared__ float red[16];
    if ((threadIdx.x & 63) == 0) red[threadIdx.x >> 6] = s;
    __syncthreads();
    if (threadIdx.x == 0) {
        float t = 0.f;
        #pragma unroll
        for (int u = 0; u < 16; u++) t += red[u];
        wsf[2] = g1[0] / sqrtf(wsf[0]);
        wsf[3] = g2[0] / sqrtf(t);
    }
}

// ---- MFMA GEMM: C(M x 1024) = A(M x GK, fp32, cvt_pk on the fly) * B(GK x 1024)
//      B bf16 [1024][GK] row-major (n-major, k contiguous), staged via global_load_lds
//      with XOR-swizzled source (proven conflict-free, round-1 counters = 0).
//      A fp32 reg-staged -> cvt_pk -> ds_write to 72-padded LDS (2-way aliasing, free).
// MAIN=true : fused epilogue  partial[row][tx*2+wn] = sum_cols relu(s1*(acc+hq)+b1)*W2
// MAIN=false: writes raw acc to outp[row*1024 + col]   (the hq pass)
// Tiles: BM=BN=128, BK=64. 256 threads = 4 waves (2x2), each wave 64x64 via 4x4 MFMA.
// XCD swizzle: n-minor so the 8 same-XCD consecutive blocks share the fp32 A panel
// (1 MB, L2-resident) -> A read from HBM ~once; B (4 MB) L2/L3-resident.
template<int GK, bool MAIN>
__global__ __launch_bounds__(256, 2)
void gemm_kernel(const float* __restrict__ Asrc,
                 const u16*   __restrict__ Bsrc,
                 float*       __restrict__ outp,
                 const float* __restrict__ hq,
                 const float* __restrict__ b1,
                 const float* __restrict__ W2,
                 const float* __restrict__ scl)
{
    __shared__ u16 As[128 * 72];
    __shared__ u16 Bs[128 * 64];

    const int tid  = threadIdx.x;
    const int lane = tid & 63;
    const int wv   = tid >> 6;
    const int wm   = wv & 1;          // wave row (0..1)
    const int wn   = wv >> 1;         // wave col (0..1)
    const int quad = lane >> 4;
    const int l15  = lane & 15;

    // bijective XCD swizzle; nwg % 8 == 0 for both grids
    const int bid  = blockIdx.y * 8 + blockIdx.x;
    const int nwg  = gridDim.x * gridDim.y;
    const int tile = (bid & 7) * (nwg >> 3) + (bid >> 3);
    const int tx   = tile & 7;
    const int ty   = tile >> 3;
    const int m0   = ty * 128;
    const int n0   = tx * 128;

    floatx4 acc[4][4];
    #pragma unroll
    for (int i = 0; i < 4; i++)
        #pragma unroll
        for (int j = 0; j < 4; j++)
            acc[i][j] = (floatx4){0.f, 0.f, 0.f, 0.f};

    for (int kt = 0; kt < GK / 64; ++kt) {
        const int k0 = kt * 64;
        __syncthreads();
        // ---- stage A: 128 rows x 64 k, fp32 -> bf16 via cvt_pk, 72-pad LDS ----
        #pragma unroll
        for (int it = 0; it < 4; ++it) {
            int s = tid + 256 * it;
            int r = s >> 3, g = s & 7;
            const float4* gp = (const float4*)(Asrc + (size_t)(m0 + r) * GK + k0 + g * 8);
            float4 f0 = gp[0];
            float4 f1 = gp[1];
            unsigned d0 = cvtpk(f0.x, f0.y), d1 = cvtpk(f0.z, f0.w);
            unsigned d2 = cvtpk(f1.x, f1.y), d3 = cvtpk(f1.z, f1.w);
            *(uint4*)(&As[r * 72 + g * 8]) = make_uint4(d0, d1, d2, d3);
        }
        // ---- stage B: bf16 via global_load_lds, XOR-swizzled source ----
        #pragma unroll
        for (int it = 0; it < 4; ++it) {
            int sbase = it * 256 + wv * 64;            // wave-uniform slot base
            int s = sbase + lane;
            int c = s >> 3, g = s & 7;
            int gs = g ^ (c & 7);
            gload16(Bsrc + (size_t)(n0 + c) * GK + k0 + gs * 8, &Bs[sbase * 8]);
        }
        __syncthreads();
        // ---- compute: 2 k-steps of 32 ----
        #pragma unroll
        for (int ks = 0; ks < 2; ++ks) {
            bf16x8 af[4], bfr[4];
            #pragma unroll
            for (int i = 0; i < 4; i++) {
                int rA = wm * 64 + i * 16 + l15;
                af[i] = *(const bf16x8*)(&As[rA * 72 + ks * 32 + quad * 8]);
            }
            #pragma unroll
            for (int j = 0; j < 4; j++) {
                int c = wn * 64 + j * 16 + l15;
                int off = (ks * 32 + quad * 8) ^ ((c & 7) << 3);
                bfr[j] = *(const bf16x8*)(&Bs[c * 64 + off]);
            }
            #pragma unroll
            for (int i = 0; i < 4; i++)
                #pragma unroll
                for (int j = 0; j < 4; j++)
                    acc[i][j] = __builtin_amdgcn_mfma_f32_16x16x32_bf16(af[i], bfr[j], acc[i][j], 0, 0, 0);
        }
    }

    if constexpr (MAIN) {
        const float s1 = scl[2];
        int   cg[4];
        float w2v[4], b1v[4];
        #pragma unroll
        for (int j = 0; j < 4; j++) {
            cg[j]  = n0 + wn * 64 + j * 16 + l15;
            w2v[j] = W2[cg[j]];
            b1v[j] = b1[cg[j]];
        }
        #pragma unroll
        for (int i = 0; i < 4; i++) {
            #pragma unroll
            for (int r = 0; r < 4; r++) {
                const int mg = m0 + wm * 64 + i * 16 + quad * 4 + r;
                const int bk = mg / NN;
                float p = 0.f;
                #pragma unroll
                for (int j = 0; j < 4; j++) {
                    float pre = s1 * (acc[i][j][r] + hq[(size_t)bk * NUM_HID + cg[j]]) + b1v[j];
                    p += fmaxf(pre, 0.f) * w2v[j];
                }
                // reduce over the 16 column-lanes of this quad (row is quad-local)
                p += __shfl_xor(p, 1);
                p += __shfl_xor(p, 2);
                p += __shfl_xor(p, 4);
                p += __shfl_xor(p, 8);
                if (l15 == 0)
                    outp[(size_t)mg * 16 + tx * 2 + wn] = p;
            }
        }
    } else {
        #pragma unroll
        for (int i = 0; i < 4; i++)
            #pragma unroll
            for (int r = 0; r < 4; r++) {
                const int mg = m0 + wm * 64 + i * 16 + quad * 4 + r;
                #pragma unroll
                for (int j = 0; j < 4; j++) {
                    const int c = n0 + wn * 64 + j * 16 + l15;
                    outp[(size_t)mg * NUM_HID + c] = acc[i][j][r];
                }
            }
    }
}

// ---- softmax over K=12 per (b,n); logits = s2*sum(partials) + b2 ----
__global__ void softmax_kernel(const float* __restrict__ part,
                               const float* __restrict__ scl,
                               const float* __restrict__ b2,
                               float* __restrict__ out)
{
    int t = blockIdx.x * 64 + threadIdx.x;   // grid 36*64 = 2304 exact
    int b = t / NN, n = t % NN;
    float s2 = scl[3], bias = b2[0];
    float lg[KK];
    float mx = -1e30f;
    #pragma unroll
    for (int k = 0; k < KK; k++) {
        int m = (b * KK + k) * NN + n;
        const float4* pp = (const float4*)(part + (size_t)m * 16);
        float4 a0 = pp[0], a1 = pp[1], a2 = pp[2], a3 = pp[3];
        float s = (a0.x + a0.y + a0.z + a0.w) + (a1.x + a1.y + a1.z + a1.w)
                + (a2.x + a2.y + a2.z + a2.w) + (a3.x + a3.y + a3.z + a3.w);
        lg[k] = s2 * s + bias;
        mx = fmaxf(mx, lg[k]);
    }
    float den = 0.f;
    #pragma unroll
    for (int k = 0; k < KK; k++) { lg[k] = expf(lg[k] - mx); den += lg[k]; }
    float inv = 1.0f / den;
    #pragma unroll
    for (int k = 0; k < KK; k++) out[(size_t)((b * KK + k) * NN + n)] = lg[k] * inv;
}

extern "C" void kernel_launch(void* const* d_in, const int* in_sizes, int n_in,
                              void* d_out, int out_size, void* d_ws, size_t ws_size,
                              hipStream_t stream)
{
    (void)in_sizes; (void)n_in; (void)out_size; (void)ws_size;
    const float* v  = (const float*)d_in[0];
    const float* q  = (const float*)d_in[1];
    const float* W1 = (const float*)d_in[2];
    const float* g1 = (const float*)d_in[3];
    const float* b1 = (const float*)d_in[4];
    const float* W2 = (const float*)d_in[5];
    const float* g2 = (const float*)d_in[6];
    const float* b2 = (const float*)d_in[7];
    float* out = (float*)d_out;

    // ws layout (bytes):
    //   0      : 4 floats  [w1_sumsq, unused, s1, s2]
    //   16     : hq  fp32 [768][1024]            (3,145,728 B)
    //   3145744: W1v bf16 [1024][2048]           (4,194,304 B)
    //   7340048: W1q bf16 [1024][1024]           (2,097,152 B)
    //   9437200: part fp32 [27648][16]           (1,769,472 B)  -> total ~11.2 MB
    char*  ws   = (char*)d_ws;
    float* wsf  = (float*)ws;
    float* hq   = (float*)(ws + 16);
    u16*   W1v  = (u16*)  (ws + 16 + 3145728);
    u16*   W1q  = (u16*)  (ws + 16 + 3145728 + 4194304);
    float* part = (float*)(ws + 16 + 3145728 + 4194304 + 2097152);

    hipMemsetAsync(d_ws, 0, 16, stream);
    // convert W1 (+ fused ||W1||^2 atomics)
    convert_w1_kernel<<<1536, 256, 0, stream>>>(W1, W1v, W1q, wsf);
    scale_kernel<<<1, 1024, 0, stream>>>(W2, g1, g2, wsf);
    // hq = q @ W1q^T (raw, unscaled):  M=768 -> grid (8 ntiles, 6 mtiles)
    gemm_kernel<Q_DIM, false><<<dim3(8, 6), 256, 0, stream>>>(
        q, W1q, hq, nullptr, nullptr, nullptr, wsf);
    // main: per-row partial logits, fp32 A converted in-kernel
    gemm_kernel<V_DIM, true><<<dim3(8, 216), 256, 0, stream>>>(
        v, W1v, part, hq, b1, W2, wsf);
    softmax_kernel<<<36, 64, 0, stream>>>(part, wsf, b2, out);
}